// Round 9
// baseline (333.798 us; speedup 1.0000x reference)
//
#include <hip/hip_runtime.h>
#include <hip/hip_bf16.h>

typedef __bf16 bf16_t;
typedef __attribute__((ext_vector_type(8))) __bf16 bfrag;   // 8 bf16 = 4 VGPRs (MFMA A/B frag)
typedef __attribute__((ext_vector_type(4))) __bf16 bf16x4;  // 8B packed store
typedef __attribute__((ext_vector_type(4))) float f32x4;    // MFMA C/D frag

#define SEQ    4096
#define NDIM   1024
#define NHEAD  16
#define HD     64
#define NBATCH 2
#define MROWS  (NBATCH * SEQ)   // 8192
#define LQK    2048             // fused Q|K row stride
#define PSTR   76               // Pw key-stride (bank-friendly, 0 conflicts in R7)

// async 16B global -> LDS (m97 pattern). l must be wave-uniform; lane i lands at l + i*16.
__device__ __forceinline__ void gload_lds16(const bf16_t* g, bf16_t* l) {
    __builtin_amdgcn_global_load_lds(
        (const __attribute__((address_space(1))) unsigned int*)g,
        (__attribute__((address_space(3))) unsigned int*)l,
        16, 0, 0);
}

// ---------------------------------------------------------------------------
// GEMM: C[M,N] = A[M,K] @ W[N,K]^T + bias   (bf16 in, f32 acc, OT out)
// m97 structure: 128x128 tile, BK=32, global_load_lds width-16 staging.
// Column blocks with col0 >= 2048 are written TRANSPOSED into Vt[b][h][d][s].
// ---------------------------------------------------------------------------
template <typename OT>
__global__ __launch_bounds__(256, 2)
void gemm_bt(const bf16_t* __restrict__ A, int lda,
             const bf16_t* __restrict__ W,
             const float* __restrict__ b0p, const float* __restrict__ b1p,
             const float* __restrict__ b2p,
             OT* __restrict__ C, int ldc, int K,
             bf16_t* __restrict__ VtOut)
{
    __shared__ __align__(16) bf16_t As[128 * 32];
    __shared__ __align__(16) bf16_t Bs[128 * 32];

    const int tid  = threadIdx.x;
    const int lane = tid & 63;
    const int wid  = tid >> 6;
    const int n16  = lane & 15;
    const int quad = lane >> 4;
    const int row0 = blockIdx.y * 128;
    const int col0 = blockIdx.x * 128;
    const int wrow = (wid >> 1) * 64;
    const int wcol = (wid & 1) * 64;
    const float* bias = (col0 < 1024) ? b0p : (col0 < 2048 ? b1p : b2p);
    const int bcol0 = col0 & 1023;

    f32x4 acc[4][4];
#pragma unroll
    for (int i = 0; i < 4; i++)
#pragma unroll
        for (int j = 0; j < 4; j++) acc[i][j] = (f32x4){0.f, 0.f, 0.f, 0.f};

    for (int k0 = 0; k0 < K; k0 += 32) {
#pragma unroll
        for (int it = 0; it < 2; it++) {
            int idx = tid + it * 256;          // 16B-chunk index 0..511
            int r   = idx >> 2;
            int c   = (idx & 3) * 8;
            gload_lds16(A + (size_t)(row0 + r) * lda + k0 + c, &As[(it * 256 + wid * 64) * 8]);
            gload_lds16(W + (size_t)(col0 + r) * K   + k0 + c, &Bs[(it * 256 + wid * 64) * 8]);
        }
        __syncthreads();

        bfrag af[4], bfg[4];
#pragma unroll
        for (int i = 0; i < 4; i++)
            af[i] = *(const bfrag*)(&As[(wrow + i * 16 + n16) * 32 + quad * 8]);
#pragma unroll
        for (int j = 0; j < 4; j++)
            bfg[j] = *(const bfrag*)(&Bs[(wcol + j * 16 + n16) * 32 + quad * 8]);

#pragma unroll
        for (int i = 0; i < 4; i++)
#pragma unroll
            for (int j = 0; j < 4; j++)
                acc[i][j] = __builtin_amdgcn_mfma_f32_16x16x32_bf16(af[i], bfg[j], acc[i][j], 0, 0, 0);
        __syncthreads();
    }

    if (col0 < 2048 || VtOut == nullptr) {
#pragma unroll
        for (int i = 0; i < 4; i++)
#pragma unroll
            for (int j = 0; j < 4; j++)
#pragma unroll
                for (int r = 0; r < 4; r++) {
                    int row = row0 + wrow + i * 16 + quad * 4 + r;
                    int col = wcol + j * 16 + n16;
                    float v = acc[i][j][r] + bias[bcol0 + col];
                    C[(size_t)row * ldc + col0 + col] = (OT)v;
                }
    } else {
        // V block: write transposed into Vt[(b*16+h)*64+d][s], packed 4 tokens
#pragma unroll
        for (int i = 0; i < 4; i++) {
#pragma unroll
            for (int j = 0; j < 4; j++) {
                int dg     = col0 + wcol + j * 16 + n16 - 2048;   // 0..1023
                int token0 = row0 + wrow + i * 16 + quad * 4;
                int bb     = token0 >> 12;
                float bv   = bias[bcol0 + wcol + j * 16 + n16];
                size_t vrow = ((size_t)bb * NHEAD + (dg >> 6)) * HD + (dg & 63);
                bf16x4 pk;
#pragma unroll
                for (int r = 0; r < 4; r++) pk[r] = (__bf16)(acc[i][j][r] + bv);
                *(bf16x4*)&VtOut[vrow * SEQ + (token0 & (SEQ - 1))] = pk;
            }
        }
    }
}

// ---------------------------------------------------------------------------
// fp32 -> bf16 casts
// ---------------------------------------------------------------------------
__global__ __launch_bounds__(256)
void cast_x(const float* __restrict__ s, bf16_t* __restrict__ d)
{
    size_t i = ((size_t)blockIdx.x * 256 + threadIdx.x) * 8;
    float4 a = *(const float4*)(s + i);
    float4 b = *(const float4*)(s + i + 4);
    bfrag o;
    o[0] = (__bf16)a.x; o[1] = (__bf16)a.y; o[2] = (__bf16)a.z; o[3] = (__bf16)a.w;
    o[4] = (__bf16)b.x; o[5] = (__bf16)b.y; o[6] = (__bf16)b.z; o[7] = (__bf16)b.w;
    *(bfrag*)(d + i) = o;
}

__global__ __launch_bounds__(256)
void cast_w(const float* __restrict__ wq, const float* __restrict__ wk,
            const float* __restrict__ wv, const float* __restrict__ wo,
            bf16_t* __restrict__ d)   // d = [Wq|Wk|Wv|Wo] bf16
{
    size_t t   = (size_t)blockIdx.x * 256 + threadIdx.x;   // 0..524287
    int    sel = (int)(t >> 17);
    const float* s = sel == 0 ? wq : (sel == 1 ? wk : (sel == 2 ? wv : wo));
    size_t off = (t & 131071) * 8;
    float4 a = *(const float4*)(s + off);
    float4 b = *(const float4*)(s + off + 4);
    bfrag o;
    o[0] = (__bf16)a.x; o[1] = (__bf16)a.y; o[2] = (__bf16)a.z; o[3] = (__bf16)a.w;
    o[4] = (__bf16)b.x; o[5] = (__bf16)b.y; o[6] = (__bf16)b.z; o[7] = (__bf16)b.w;
    *(bfrag*)(d + (size_t)sel * 1048576 + off) = o;
}

// ---------------------------------------------------------------------------
// Flash sliding-window attention, transposed frame (S^T / O^T), 128-query
// blocks (8 waves x 16 queries), XCD-swizzled 1-D grid.
//   lin -> xcd = lin&7 owns 4 complete (b,h) pairs (K+V = 4 MB = its L2).
//   K: double-buffered LDS, register-prefetched, 1 barrier/iter, 10 iters.
//   Wave-uniform skip of fully-masked iters (~1/wave).
//   S^T = K Q^T (A from LDS); P^T -> Pw packed b64; O^T = V^T P^T (V global).
// ---------------------------------------------------------------------------
__global__ __launch_bounds__(512, 8)
void attn_win(const bf16_t* __restrict__ QK, const bf16_t* __restrict__ Vt,
              bf16_t* __restrict__ AO)
{
    __shared__ __align__(16) bf16_t Ks[2][64 * 72];     // 18432 B
    __shared__ __align__(16) bf16_t Pw[8][16 * PSTR];   // 19456 B, wave-private

    const int tid  = threadIdx.x;
    const int wid  = tid >> 6;          // 0..7
    const int lane = tid & 63;
    const int n16  = lane & 15;
    const int quad = lane >> 4;

    // XCD swizzle: each xcd (lin&7) owns bh in [4*xcd, 4*xcd+4), qtiles in order
    const int lin = blockIdx.x;          // 0..1023
    const int sub = lin >> 3;            // 0..127
    const int bh  = (lin & 7) * 4 + (sub >> 5);
    const int qt  = sub & 31;
    const int qb0 = qt * 128;

    const int b  = bh >> 4, h = bh & 15;
    const size_t bS   = (size_t)b * SEQ;
    const size_t hoff = (size_t)h * HD;
    const bf16_t* Vb  = Vt + (size_t)bh * HD * SEQ;   // [d][s]
    const int wstart  = qb0 - 512;
    const int it0     = (qb0 < 512) ? ((512 - qb0) >> 6) : 0;

    // staging map: key-row = tid>>3 (0..63), one 16B chunk per thread
    const int srow  = tid >> 3;
    const int scol0 = (tid & 7) * 8;

    // ---- Q B-frags (once): col n16 = query, k = dims ----
    const int qa    = qb0 + wid * 16 + n16;           // this lane's query
    const int qwmin = qb0 + wid * 16;
    const int qwmax = qwmin + 15;
    bfrag bq0 = *(const bfrag*)(&QK[(bS + qa) * LQK + hoff + quad * 8]);
    bfrag bq1 = *(const bfrag*)(&QK[(bS + qa) * LQK + hoff + 32 + quad * 8]);

    f32x4 ao[4];                                       // O^T: d = j*16+quad*4+r
#pragma unroll
    for (int j = 0; j < 4; j++) ao[j] = (f32x4){0.f, 0.f, 0.f, 0.f};
    float m = -1e30f, l = 0.f;

    // prefetch K for first iteration
    uint4 kp = *(const uint4*)(&QK[(bS + wstart + it0 * 64 + srow) * LQK + 1024 + hoff + scol0]);

    for (int it = it0; it < 10; ++it) {
        const int k0 = wstart + it * 64;
        const int pb = it & 1;
        *(uint4*)(&Ks[pb][srow * 72 + scol0]) = kp;
        __syncthreads();
        if (it < 9)
            kp = *(const uint4*)(&QK[(bS + wstart + (it + 1) * 64 + srow) * LQK + 1024 + hoff + scol0]);

        // wave-uniform skip: this wave's 16 queries have no valid keys here
        if (k0 > qwmax || k0 + 63 < qwmin - 511) continue;

        // ---- S^T = K Q^T : 4 key-tiles, A = K from LDS ----
        f32x4 a[4];
#pragma unroll
        for (int nt = 0; nt < 4; nt++) {
            bfrag ak0 = *(const bfrag*)(&Ks[pb][(nt * 16 + n16) * 72 + quad * 8]);
            bfrag ak1 = *(const bfrag*)(&Ks[pb][(nt * 16 + n16) * 72 + 32 + quad * 8]);
            f32x4 s4 = (f32x4){0.f, 0.f, 0.f, 0.f};
            s4 = __builtin_amdgcn_mfma_f32_16x16x32_bf16(ak0, bq0, s4, 0, 0, 0);
            s4 = __builtin_amdgcn_mfma_f32_16x16x32_bf16(ak1, bq1, s4, 0, 0, 0);
            a[nt] = s4;
        }

        const bool msk = !((k0 >= qwmax - 511) & (k0 + 63 <= qwmin));
        if (msk) {
#pragma unroll
            for (int nt = 0; nt < 4; nt++)
#pragma unroll
                for (int r = 0; r < 4; r++) {
                    int ka = k0 + nt * 16 + quad * 4 + r;   // S^T row = key
                    bool valid = (ka >= qa - 511) & (ka <= qa);
                    a[nt][r] = valid ? a[nt][r] * 0.125f : -1e30f;
                }
        } else {
#pragma unroll
            for (int nt = 0; nt < 4; nt++)
#pragma unroll
                for (int r = 0; r < 4; r++) a[nt][r] *= 0.125f;
        }

        // ---- online softmax: per-lane scalar state (query = n16) ----
        float cm = -1e30f;
#pragma unroll
        for (int nt = 0; nt < 4; nt++)
#pragma unroll
            for (int r = 0; r < 4; r++) cm = fmaxf(cm, a[nt][r]);
        cm = fmaxf(cm, __shfl_xor(cm, 16, 64));
        cm = fmaxf(cm, __shfl_xor(cm, 32, 64));
        float mn    = fmaxf(m, cm);
        float alpha = __expf(m - mn);
        m = mn;
#pragma unroll
        for (int j = 0; j < 4; j++)
#pragma unroll
            for (int r = 0; r < 4; r++) ao[j][r] *= alpha;

        // ---- p = exp(s-m); packed b64 writes into Pw [query][key] ----
        float lacc = 0.f;
#pragma unroll
        for (int nt = 0; nt < 4; nt++) {
            bf16x4 pk;
#pragma unroll
            for (int r = 0; r < 4; r++) {
                float p = __expf(a[nt][r] - m);
                if (msk && a[nt][r] <= -1e29f) p = 0.f;
                lacc += p;
                pk[r] = (__bf16)p;
            }
            *(bf16x4*)&Pw[wid][n16 * PSTR + nt * 16 + quad * 4] = pk;
        }
        l = l * alpha + lacc;              // cross-quad l-reduce deferred to epilogue

        // ---- O^T += V^T P^T : 2 k-steps of 32 keys ----
#pragma unroll
        for (int ks = 0; ks < 2; ks++) {
            bfrag bp = *(const bfrag*)(&Pw[wid][n16 * PSTR + ks * 32 + quad * 8]);
#pragma unroll
            for (int j = 0; j < 4; j++) {
                bfrag av = *(const bfrag*)(&Vb[(size_t)(j * 16 + n16) * SEQ
                                               + k0 + ks * 32 + quad * 8]);
                ao[j] = __builtin_amdgcn_mfma_f32_16x16x32_bf16(av, bp, ao[j], 0, 0, 0);
            }
        }
    }

    // ---- epilogue: reduce l across quads, store O rows (packed b64) ----
    l += __shfl_xor(l, 16, 64);
    l += __shfl_xor(l, 32, 64);
    const float inv = 1.0f / l;
#pragma unroll
    for (int j = 0; j < 4; j++) {
        bf16x4 pk;
#pragma unroll
        for (int r = 0; r < 4; r++) pk[r] = (__bf16)(ao[j][r] * inv);
        *(bf16x4*)&AO[(bS + qa) * NDIM + hoff + j * 16 + quad * 4] = pk;
    }
}

// ---------------------------------------------------------------------------
extern "C" void kernel_launch(void* const* d_in, const int* in_sizes, int n_in,
                              void* d_out, int out_size, void* d_ws, size_t ws_size,
                              hipStream_t stream)
{
    const float* x  = (const float*)d_in[0];
    const float* Wq = (const float*)d_in[1];
    const float* bq = (const float*)d_in[2];
    const float* Wk = (const float*)d_in[3];
    const float* bk = (const float*)d_in[4];
    const float* Wv = (const float*)d_in[5];
    const float* bv = (const float*)d_in[6];
    const float* Wo = (const float*)d_in[7];
    const float* bo = (const float*)d_in[8];
    float* out = (float*)d_out;

    // ws: QKb [8192][2048] bf16 (32 MiB) | AbX [8192][1024] bf16 (16 MiB)
    //     Wc [Wq|Wk|Wv|Wo] bf16 (8 MiB)
    const size_t QK_E = (size_t)MROWS * LQK;
    const size_t X_E  = (size_t)MROWS * NDIM;
    if (ws_size < (QK_E + X_E + 4u * 1048576u) * sizeof(bf16_t)) return;

    bf16_t* QKb = (bf16_t*)d_ws;
    bf16_t* AbX = QKb + QK_E;
    bf16_t* Wc  = AbX + X_E;
    bf16_t* Wob = Wc + 3u * 1048576u;
    bf16_t* Vtg = (bf16_t*)d_out;   // 16.8 MB scratch inside the 33.5 MB out buf;
                                    // dead before the O-proj overwrites d_out.

    dim3 blk(256);

    cast_x<<<dim3(4096), blk, 0, stream>>>(x, AbX);
    cast_w<<<dim3(2048), blk, 0, stream>>>(Wq, Wk, Wv, Wo, Wc);

    // fused QKV projection: Q,K -> QKb (stride 2048); V -> Vtg transposed
    gemm_bt<bf16_t><<<dim3(3072 / 128, MROWS / 128), blk, 0, stream>>>(
        AbX, NDIM, Wc, bq, bk, bv, QKb, LQK, NDIM, Vtg);

    attn_win<<<dim3(1024), dim3(512), 0, stream>>>(QKb, Vtg, AbX);

    // output projection: [8192,1024] x [1024,1024]^T -> fp32 out
    gemm_bt<float><<<dim3(NDIM / 128, MROWS / 128), blk, 0, stream>>>(
        AbX, NDIM, Wob, bo, bo, bo, out, NDIM, NDIM, nullptr);
}

// Round 10
// 277.054 us; speedup vs baseline: 1.2048x; 1.2048x over previous
//
#include <hip/hip_runtime.h>
#include <hip/hip_bf16.h>

typedef __bf16 bf16_t;
typedef __attribute__((ext_vector_type(8))) __bf16 bfrag;   // 8 bf16 = 4 VGPRs (MFMA A/B frag)
typedef __attribute__((ext_vector_type(4))) __bf16 bf16x4;  // 8B packed store
typedef __attribute__((ext_vector_type(4))) float f32x4;    // MFMA C/D frag

#define SEQ    4096
#define NDIM   1024
#define NHEAD  16
#define HD     64
#define NBATCH 2
#define MROWS  (NBATCH * SEQ)   // 8192
#define LQK    2048             // fused Q|K row stride
#define PSTR   76               // Pw key-stride (bank-friendly, 0 conflicts in R7)

// async 16B global -> LDS (m97 pattern). l must be wave-uniform; lane i lands at l + i*16.
__device__ __forceinline__ void gload_lds16(const bf16_t* g, bf16_t* l) {
    __builtin_amdgcn_global_load_lds(
        (const __attribute__((address_space(1))) unsigned int*)g,
        (__attribute__((address_space(3))) unsigned int*)l,
        16, 0, 0);
}

// ---------------------------------------------------------------------------
// GEMM: C[M,N] = A[M,K] @ W[N,K]^T + bias   (bf16 in, f32 acc, OT out)
// m97 structure: 128x128 tile, BK=32, global_load_lds width-16 staging.
// Column blocks with col0 >= 2048 are written TRANSPOSED into Vt[b][h][d][s].
// ---------------------------------------------------------------------------
template <typename OT>
__global__ __launch_bounds__(256, 2)
void gemm_bt(const bf16_t* __restrict__ A, int lda,
             const bf16_t* __restrict__ W,
             const float* __restrict__ b0p, const float* __restrict__ b1p,
             const float* __restrict__ b2p,
             OT* __restrict__ C, int ldc, int K,
             bf16_t* __restrict__ VtOut)
{
    __shared__ __align__(16) bf16_t As[128 * 32];
    __shared__ __align__(16) bf16_t Bs[128 * 32];

    const int tid  = threadIdx.x;
    const int lane = tid & 63;
    const int wid  = tid >> 6;
    const int n16  = lane & 15;
    const int quad = lane >> 4;
    const int row0 = blockIdx.y * 128;
    const int col0 = blockIdx.x * 128;
    const int wrow = (wid >> 1) * 64;
    const int wcol = (wid & 1) * 64;
    const float* bias = (col0 < 1024) ? b0p : (col0 < 2048 ? b1p : b2p);
    const int bcol0 = col0 & 1023;

    f32x4 acc[4][4];
#pragma unroll
    for (int i = 0; i < 4; i++)
#pragma unroll
        for (int j = 0; j < 4; j++) acc[i][j] = (f32x4){0.f, 0.f, 0.f, 0.f};

    for (int k0 = 0; k0 < K; k0 += 32) {
#pragma unroll
        for (int it = 0; it < 2; it++) {
            int idx = tid + it * 256;          // 16B-chunk index 0..511
            int r   = idx >> 2;
            int c   = (idx & 3) * 8;
            gload_lds16(A + (size_t)(row0 + r) * lda + k0 + c, &As[(it * 256 + wid * 64) * 8]);
            gload_lds16(W + (size_t)(col0 + r) * K   + k0 + c, &Bs[(it * 256 + wid * 64) * 8]);
        }
        __syncthreads();

        bfrag af[4], bfg[4];
#pragma unroll
        for (int i = 0; i < 4; i++)
            af[i] = *(const bfrag*)(&As[(wrow + i * 16 + n16) * 32 + quad * 8]);
#pragma unroll
        for (int j = 0; j < 4; j++)
            bfg[j] = *(const bfrag*)(&Bs[(wcol + j * 16 + n16) * 32 + quad * 8]);

#pragma unroll
        for (int i = 0; i < 4; i++)
#pragma unroll
            for (int j = 0; j < 4; j++)
                acc[i][j] = __builtin_amdgcn_mfma_f32_16x16x32_bf16(af[i], bfg[j], acc[i][j], 0, 0, 0);
        __syncthreads();
    }

    if (col0 < 2048 || VtOut == nullptr) {
#pragma unroll
        for (int i = 0; i < 4; i++)
#pragma unroll
            for (int j = 0; j < 4; j++)
#pragma unroll
                for (int r = 0; r < 4; r++) {
                    int row = row0 + wrow + i * 16 + quad * 4 + r;
                    int col = wcol + j * 16 + n16;
                    float v = acc[i][j][r] + bias[bcol0 + col];
                    C[(size_t)row * ldc + col0 + col] = (OT)v;
                }
    } else {
        // V block: write transposed into Vt[(b*16+h)*64+d][s], packed 4 tokens
#pragma unroll
        for (int i = 0; i < 4; i++) {
#pragma unroll
            for (int j = 0; j < 4; j++) {
                int dg     = col0 + wcol + j * 16 + n16 - 2048;   // 0..1023
                int token0 = row0 + wrow + i * 16 + quad * 4;
                int bb     = token0 >> 12;
                float bv   = bias[bcol0 + wcol + j * 16 + n16];
                size_t vrow = ((size_t)bb * NHEAD + (dg >> 6)) * HD + (dg & 63);
                bf16x4 pk;
#pragma unroll
                for (int r = 0; r < 4; r++) pk[r] = (__bf16)(acc[i][j][r] + bv);
                *(bf16x4*)&VtOut[vrow * SEQ + (token0 & (SEQ - 1))] = pk;
            }
        }
    }
}

// ---------------------------------------------------------------------------
// fp32 -> bf16 casts
// ---------------------------------------------------------------------------
__global__ __launch_bounds__(256)
void cast_x(const float* __restrict__ s, bf16_t* __restrict__ d)
{
    size_t i = ((size_t)blockIdx.x * 256 + threadIdx.x) * 8;
    float4 a = *(const float4*)(s + i);
    float4 b = *(const float4*)(s + i + 4);
    bfrag o;
    o[0] = (__bf16)a.x; o[1] = (__bf16)a.y; o[2] = (__bf16)a.z; o[3] = (__bf16)a.w;
    o[4] = (__bf16)b.x; o[5] = (__bf16)b.y; o[6] = (__bf16)b.z; o[7] = (__bf16)b.w;
    *(bfrag*)(d + i) = o;
}

__global__ __launch_bounds__(256)
void cast_w(const float* __restrict__ wq, const float* __restrict__ wk,
            const float* __restrict__ wv, const float* __restrict__ wo,
            bf16_t* __restrict__ d)   // d = [Wq|Wk|Wv|Wo] bf16
{
    size_t t   = (size_t)blockIdx.x * 256 + threadIdx.x;   // 0..524287
    int    sel = (int)(t >> 17);
    const float* s = sel == 0 ? wq : (sel == 1 ? wk : (sel == 2 ? wv : wo));
    size_t off = (t & 131071) * 8;
    float4 a = *(const float4*)(s + off);
    float4 b = *(const float4*)(s + off + 4);
    bfrag o;
    o[0] = (__bf16)a.x; o[1] = (__bf16)a.y; o[2] = (__bf16)a.z; o[3] = (__bf16)a.w;
    o[4] = (__bf16)b.x; o[5] = (__bf16)b.y; o[6] = (__bf16)b.z; o[7] = (__bf16)b.w;
    *(bfrag*)(d + (size_t)sel * 1048576 + off) = o;
}

// ---------------------------------------------------------------------------
// Flash sliding-window attention, transposed frame (S^T / O^T), 128-query
// blocks (8 waves x 16 queries), XCD-swizzled 1-D grid.
//   lin -> xcd = lin&7 owns 4 complete (b,h) pairs (K+V = 4 MB = its L2).
//   K: double-buffered LDS, register-prefetched, 1 barrier/iter, 10 iters.
//   Wave-uniform skip of fully-masked iters (~1/wave).
//   S^T = K Q^T (A from LDS); P^T -> Pw packed b64; O^T = V^T P^T (V global).
// launch_bounds (512,4): VGPR cap 128 — R9's (512,8) forced 32 VGPRs and
// spilled 115 MB to scratch (WRITE_SIZE 16->131 MB). Need ~60 regs live.
// ---------------------------------------------------------------------------
__global__ __launch_bounds__(512, 4)
void attn_win(const bf16_t* __restrict__ QK, const bf16_t* __restrict__ Vt,
              bf16_t* __restrict__ AO)
{
    __shared__ __align__(16) bf16_t Ks[2][64 * 72];     // 18432 B
    __shared__ __align__(16) bf16_t Pw[8][16 * PSTR];   // 19456 B, wave-private

    const int tid  = threadIdx.x;
    const int wid  = tid >> 6;          // 0..7
    const int lane = tid & 63;
    const int n16  = lane & 15;
    const int quad = lane >> 4;

    // XCD swizzle: each xcd (lin&7) owns bh in [4*xcd, 4*xcd+4), qtiles in order
    const int lin = blockIdx.x;          // 0..1023
    const int sub = lin >> 3;            // 0..127
    const int bh  = (lin & 7) * 4 + (sub >> 5);
    const int qt  = sub & 31;
    const int qb0 = qt * 128;

    const int b  = bh >> 4, h = bh & 15;
    const size_t bS   = (size_t)b * SEQ;
    const size_t hoff = (size_t)h * HD;
    const bf16_t* Vb  = Vt + (size_t)bh * HD * SEQ;   // [d][s]
    const int wstart  = qb0 - 512;
    const int it0     = (qb0 < 512) ? ((512 - qb0) >> 6) : 0;

    // staging map: key-row = tid>>3 (0..63), one 16B chunk per thread
    const int srow  = tid >> 3;
    const int scol0 = (tid & 7) * 8;

    // ---- Q B-frags (once): col n16 = query, k = dims ----
    const int qa    = qb0 + wid * 16 + n16;           // this lane's query
    const int qwmin = qb0 + wid * 16;
    const int qwmax = qwmin + 15;
    bfrag bq0 = *(const bfrag*)(&QK[(bS + qa) * LQK + hoff + quad * 8]);
    bfrag bq1 = *(const bfrag*)(&QK[(bS + qa) * LQK + hoff + 32 + quad * 8]);

    f32x4 ao[4];                                       // O^T: d = j*16+quad*4+r
#pragma unroll
    for (int j = 0; j < 4; j++) ao[j] = (f32x4){0.f, 0.f, 0.f, 0.f};
    float m = -1e30f, l = 0.f;

    // prefetch K for first iteration
    uint4 kp = *(const uint4*)(&QK[(bS + wstart + it0 * 64 + srow) * LQK + 1024 + hoff + scol0]);

    for (int it = it0; it < 10; ++it) {
        const int k0 = wstart + it * 64;
        const int pb = it & 1;
        *(uint4*)(&Ks[pb][srow * 72 + scol0]) = kp;
        __syncthreads();
        if (it < 9)
            kp = *(const uint4*)(&QK[(bS + wstart + (it + 1) * 64 + srow) * LQK + 1024 + hoff + scol0]);

        // wave-uniform skip: this wave's 16 queries have no valid keys here
        if (k0 > qwmax || k0 + 63 < qwmin - 511) continue;

        // ---- S^T = K Q^T : 4 key-tiles, A = K from LDS ----
        f32x4 a[4];
#pragma unroll
        for (int nt = 0; nt < 4; nt++) {
            bfrag ak0 = *(const bfrag*)(&Ks[pb][(nt * 16 + n16) * 72 + quad * 8]);
            bfrag ak1 = *(const bfrag*)(&Ks[pb][(nt * 16 + n16) * 72 + 32 + quad * 8]);
            f32x4 s4 = (f32x4){0.f, 0.f, 0.f, 0.f};
            s4 = __builtin_amdgcn_mfma_f32_16x16x32_bf16(ak0, bq0, s4, 0, 0, 0);
            s4 = __builtin_amdgcn_mfma_f32_16x16x32_bf16(ak1, bq1, s4, 0, 0, 0);
            a[nt] = s4;
        }

        const bool msk = !((k0 >= qwmax - 511) & (k0 + 63 <= qwmin));
        if (msk) {
#pragma unroll
            for (int nt = 0; nt < 4; nt++)
#pragma unroll
                for (int r = 0; r < 4; r++) {
                    int ka = k0 + nt * 16 + quad * 4 + r;   // S^T row = key
                    bool valid = (ka >= qa - 511) & (ka <= qa);
                    a[nt][r] = valid ? a[nt][r] * 0.125f : -1e30f;
                }
        } else {
#pragma unroll
            for (int nt = 0; nt < 4; nt++)
#pragma unroll
                for (int r = 0; r < 4; r++) a[nt][r] *= 0.125f;
        }

        // ---- online softmax: per-lane scalar state (query = n16) ----
        float cm = -1e30f;
#pragma unroll
        for (int nt = 0; nt < 4; nt++)
#pragma unroll
            for (int r = 0; r < 4; r++) cm = fmaxf(cm, a[nt][r]);
        cm = fmaxf(cm, __shfl_xor(cm, 16, 64));
        cm = fmaxf(cm, __shfl_xor(cm, 32, 64));
        float mn    = fmaxf(m, cm);
        float alpha = __expf(m - mn);
        m = mn;
#pragma unroll
        for (int j = 0; j < 4; j++)
#pragma unroll
            for (int r = 0; r < 4; r++) ao[j][r] *= alpha;

        // ---- p = exp(s-m); packed b64 writes into Pw [query][key] ----
        float lacc = 0.f;
#pragma unroll
        for (int nt = 0; nt < 4; nt++) {
            bf16x4 pk;
#pragma unroll
            for (int r = 0; r < 4; r++) {
                float p = __expf(a[nt][r] - m);
                if (msk && a[nt][r] <= -1e29f) p = 0.f;
                lacc += p;
                pk[r] = (__bf16)p;
            }
            *(bf16x4*)&Pw[wid][n16 * PSTR + nt * 16 + quad * 4] = pk;
        }
        l = l * alpha + lacc;              // cross-quad l-reduce deferred to epilogue

        // ---- O^T += V^T P^T : 2 k-steps of 32 keys ----
#pragma unroll
        for (int ks = 0; ks < 2; ks++) {
            bfrag bp = *(const bfrag*)(&Pw[wid][n16 * PSTR + ks * 32 + quad * 8]);
#pragma unroll
            for (int j = 0; j < 4; j++) {
                bfrag av = *(const bfrag*)(&Vb[(size_t)(j * 16 + n16) * SEQ
                                               + k0 + ks * 32 + quad * 8]);
                ao[j] = __builtin_amdgcn_mfma_f32_16x16x32_bf16(av, bp, ao[j], 0, 0, 0);
            }
        }
    }

    // ---- epilogue: reduce l across quads, store O rows (packed b64) ----
    l += __shfl_xor(l, 16, 64);
    l += __shfl_xor(l, 32, 64);
    const float inv = 1.0f / l;
#pragma unroll
    for (int j = 0; j < 4; j++) {
        bf16x4 pk;
#pragma unroll
        for (int r = 0; r < 4; r++) pk[r] = (__bf16)(ao[j][r] * inv);
        *(bf16x4*)&AO[(bS + qa) * NDIM + hoff + j * 16 + quad * 4] = pk;
    }
}

// ---------------------------------------------------------------------------
extern "C" void kernel_launch(void* const* d_in, const int* in_sizes, int n_in,
                              void* d_out, int out_size, void* d_ws, size_t ws_size,
                              hipStream_t stream)
{
    const float* x  = (const float*)d_in[0];
    const float* Wq = (const float*)d_in[1];
    const float* bq = (const float*)d_in[2];
    const float* Wk = (const float*)d_in[3];
    const float* bk = (const float*)d_in[4];
    const float* Wv = (const float*)d_in[5];
    const float* bv = (const float*)d_in[6];
    const float* Wo = (const float*)d_in[7];
    const float* bo = (const float*)d_in[8];
    float* out = (float*)d_out;

    // ws: QKb [8192][2048] bf16 (32 MiB) | AbX [8192][1024] bf16 (16 MiB)
    //     Wc [Wq|Wk|Wv|Wo] bf16 (8 MiB)
    const size_t QK_E = (size_t)MROWS * LQK;
    const size_t X_E  = (size_t)MROWS * NDIM;
    if (ws_size < (QK_E + X_E + 4u * 1048576u) * sizeof(bf16_t)) return;

    bf16_t* QKb = (bf16_t*)d_ws;
    bf16_t* AbX = QKb + QK_E;
    bf16_t* Wc  = AbX + X_E;
    bf16_t* Wob = Wc + 3u * 1048576u;
    bf16_t* Vtg = (bf16_t*)d_out;   // 16.8 MB scratch inside the 33.5 MB out buf;
                                    // dead before the O-proj overwrites d_out.

    dim3 blk(256);

    cast_x<<<dim3(4096), blk, 0, stream>>>(x, AbX);
    cast_w<<<dim3(2048), blk, 0, stream>>>(Wq, Wk, Wv, Wo, Wc);

    // fused QKV projection: Q,K -> QKb (stride 2048); V -> Vtg transposed
    gemm_bt<bf16_t><<<dim3(3072 / 128, MROWS / 128), blk, 0, stream>>>(
        AbX, NDIM, Wc, bq, bk, bv, QKb, LQK, NDIM, Vtg);

    attn_win<<<dim3(1024), dim3(512), 0, stream>>>(QKb, Vtg, AbX);

    // output projection: [8192,1024] x [1024,1024]^T -> fp32 out
    gemm_bt<float><<<dim3(NDIM / 128, MROWS / 128), blk, 0, stream>>>(
        AbX, NDIM, Wob, bo, bo, bo, out, NDIM, NDIM, nullptr);
}

// Round 11
// 271.048 us; speedup vs baseline: 1.2315x; 1.0222x over previous
//
#include <hip/hip_runtime.h>
#include <hip/hip_bf16.h>

typedef __bf16 bf16_t;
typedef __attribute__((ext_vector_type(8))) __bf16 bfrag;   // 8 bf16 = 4 VGPRs (MFMA A/B frag)
typedef __attribute__((ext_vector_type(4))) __bf16 bf16x4;  // 8B packed store
typedef __attribute__((ext_vector_type(4))) float f32x4;    // MFMA C/D frag

#define SEQ    4096
#define NDIM   1024
#define NHEAD  16
#define HD     64
#define NBATCH 2
#define MROWS  (NBATCH * SEQ)   // 8192
#define LQK    2048             // fused Q|K row stride
#define PSTR   76               // Pw key-stride (conflict-free b64 writes, verified R7-R10)

// async 16B global -> LDS (m97 pattern). l must be wave-uniform; lane i lands at l + i*16.
__device__ __forceinline__ void gload_lds16(const bf16_t* g, bf16_t* l) {
    __builtin_amdgcn_global_load_lds(
        (const __attribute__((address_space(1))) unsigned int*)g,
        (__attribute__((address_space(3))) unsigned int*)l,
        16, 0, 0);
}

// ---------------------------------------------------------------------------
// GEMM: C[M,N] = A[M,K] @ W[N,K]^T + bias   (bf16 in, f32 acc, OT out)
// m97 structure: 128x128 tile, BK=32, global_load_lds width-16 staging.
// qscale: bias scale applied to columns < 1024 (softmax 1/8 pre-baked into
// Wq by cast_w; bias needs the same factor). Pass 1.0 for other GEMMs.
// Column blocks with col0 >= 2048 are written TRANSPOSED into Vt[b][h][d][s].
// ---------------------------------------------------------------------------
template <typename OT>
__global__ __launch_bounds__(256, 2)
void gemm_bt(const bf16_t* __restrict__ A, int lda,
             const bf16_t* __restrict__ W,
             const float* __restrict__ b0p, const float* __restrict__ b1p,
             const float* __restrict__ b2p, float qscale,
             OT* __restrict__ C, int ldc, int K,
             bf16_t* __restrict__ VtOut)
{
    __shared__ __align__(16) bf16_t As[128 * 32];
    __shared__ __align__(16) bf16_t Bs[128 * 32];

    const int tid  = threadIdx.x;
    const int lane = tid & 63;
    const int wid  = tid >> 6;
    const int n16  = lane & 15;
    const int quad = lane >> 4;
    const int row0 = blockIdx.y * 128;
    const int col0 = blockIdx.x * 128;
    const int wrow = (wid >> 1) * 64;
    const int wcol = (wid & 1) * 64;
    const float* bias = (col0 < 1024) ? b0p : (col0 < 2048 ? b1p : b2p);
    const float bsc = (col0 < 1024) ? qscale : 1.0f;
    const int bcol0 = col0 & 1023;

    f32x4 acc[4][4];
#pragma unroll
    for (int i = 0; i < 4; i++)
#pragma unroll
        for (int j = 0; j < 4; j++) acc[i][j] = (f32x4){0.f, 0.f, 0.f, 0.f};

    for (int k0 = 0; k0 < K; k0 += 32) {
#pragma unroll
        for (int it = 0; it < 2; it++) {
            int idx = tid + it * 256;          // 16B-chunk index 0..511
            int r   = idx >> 2;
            int c   = (idx & 3) * 8;
            gload_lds16(A + (size_t)(row0 + r) * lda + k0 + c, &As[(it * 256 + wid * 64) * 8]);
            gload_lds16(W + (size_t)(col0 + r) * K   + k0 + c, &Bs[(it * 256 + wid * 64) * 8]);
        }
        __syncthreads();

        bfrag af[4], bfg[4];
#pragma unroll
        for (int i = 0; i < 4; i++)
            af[i] = *(const bfrag*)(&As[(wrow + i * 16 + n16) * 32 + quad * 8]);
#pragma unroll
        for (int j = 0; j < 4; j++)
            bfg[j] = *(const bfrag*)(&Bs[(wcol + j * 16 + n16) * 32 + quad * 8]);

#pragma unroll
        for (int i = 0; i < 4; i++)
#pragma unroll
            for (int j = 0; j < 4; j++)
                acc[i][j] = __builtin_amdgcn_mfma_f32_16x16x32_bf16(af[i], bfg[j], acc[i][j], 0, 0, 0);
        __syncthreads();
    }

    if (col0 < 2048 || VtOut == nullptr) {
#pragma unroll
        for (int i = 0; i < 4; i++)
#pragma unroll
            for (int j = 0; j < 4; j++)
#pragma unroll
                for (int r = 0; r < 4; r++) {
                    int row = row0 + wrow + i * 16 + quad * 4 + r;
                    int col = wcol + j * 16 + n16;
                    float v = acc[i][j][r] + bias[bcol0 + col] * bsc;
                    C[(size_t)row * ldc + col0 + col] = (OT)v;
                }
    } else {
        // V block: write transposed into Vt[(b*16+h)*64+d][s], packed 4 tokens
#pragma unroll
        for (int i = 0; i < 4; i++) {
#pragma unroll
            for (int j = 0; j < 4; j++) {
                int dg     = col0 + wcol + j * 16 + n16 - 2048;   // 0..1023
                int token0 = row0 + wrow + i * 16 + quad * 4;
                int bb     = token0 >> 12;
                float bv   = bias[bcol0 + wcol + j * 16 + n16];
                size_t vrow = ((size_t)bb * NHEAD + (dg >> 6)) * HD + (dg & 63);
                bf16x4 pk;
#pragma unroll
                for (int r = 0; r < 4; r++) pk[r] = (__bf16)(acc[i][j][r] + bv);
                *(bf16x4*)&VtOut[vrow * SEQ + (token0 & (SEQ - 1))] = pk;
            }
        }
    }
}

// ---------------------------------------------------------------------------
// fp32 -> bf16 casts
// ---------------------------------------------------------------------------
__global__ __launch_bounds__(256)
void cast_x(const float* __restrict__ s, bf16_t* __restrict__ d)
{
    size_t i = ((size_t)blockIdx.x * 256 + threadIdx.x) * 8;
    float4 a = *(const float4*)(s + i);
    float4 b = *(const float4*)(s + i + 4);
    bfrag o;
    o[0] = (__bf16)a.x; o[1] = (__bf16)a.y; o[2] = (__bf16)a.z; o[3] = (__bf16)a.w;
    o[4] = (__bf16)b.x; o[5] = (__bf16)b.y; o[6] = (__bf16)b.z; o[7] = (__bf16)b.w;
    *(bfrag*)(d + i) = o;
}

__global__ __launch_bounds__(256)
void cast_w(const float* __restrict__ wq, const float* __restrict__ wk,
            const float* __restrict__ wv, const float* __restrict__ wo,
            bf16_t* __restrict__ d)   // d = [Wq*0.125|Wk|Wv|Wo] bf16
{
    size_t t   = (size_t)blockIdx.x * 256 + threadIdx.x;   // 0..524287
    int    sel = (int)(t >> 17);
    const float* s = sel == 0 ? wq : (sel == 1 ? wk : (sel == 2 ? wv : wo));
    const float sc = (sel == 0) ? 0.125f : 1.0f;   // pre-bake softmax scale into Wq
    size_t off = (t & 131071) * 8;
    float4 a = *(const float4*)(s + off);
    float4 b = *(const float4*)(s + off + 4);
    bfrag o;
    o[0] = (__bf16)(a.x * sc); o[1] = (__bf16)(a.y * sc);
    o[2] = (__bf16)(a.z * sc); o[3] = (__bf16)(a.w * sc);
    o[4] = (__bf16)(b.x * sc); o[5] = (__bf16)(b.y * sc);
    o[6] = (__bf16)(b.z * sc); o[7] = (__bf16)(b.w * sc);
    *(bfrag*)(d + (size_t)sel * 1048576 + off) = o;
}

// ---------------------------------------------------------------------------
// Flash sliding-window attention, transposed frame (S^T / O^T).
// 256-thread blocks, 4 waves x 32 queries (two independent 16-query chains
// per wave -> 2x ILP; K LDS-frags and V global-frags shared by both chains).
// XCD-swizzled grid (R10: FETCH 145->24.6 MB). Scores come pre-scaled
// (Wq,bq carry the 1/8). exp(-1e30 - m) underflows to 0; all-invalid early
// iters self-heal via alpha=0 at the first real key.
// ---------------------------------------------------------------------------
__global__ __launch_bounds__(256, 4)
void attn_win(const bf16_t* __restrict__ QK, const bf16_t* __restrict__ Vt,
              bf16_t* __restrict__ AO)
{
    __shared__ __align__(16) bf16_t Ks[2][64 * 72];     // 18432 B
    __shared__ __align__(16) bf16_t Pw[4][32 * PSTR];   // 19456 B, wave-private

    const int tid  = threadIdx.x;
    const int wid  = tid >> 6;          // 0..3
    const int lane = tid & 63;
    const int n16  = lane & 15;
    const int quad = lane >> 4;

    // XCD swizzle: each xcd (lin&7) owns bh in [4*xcd, 4*xcd+4)
    const int lin = blockIdx.x;          // 0..1023
    const int sub = lin >> 3;            // 0..127
    const int bh  = (lin & 7) * 4 + (sub >> 5);
    const int qt  = sub & 31;
    const int qb0 = qt * 128;

    const int b  = bh >> 4, h = bh & 15;
    const size_t bS   = (size_t)b * SEQ;
    const size_t hoff = (size_t)h * HD;
    const bf16_t* Vb  = Vt + (size_t)bh * HD * SEQ;   // [d][s]
    const int wstart  = qb0 - 512;
    const int it0     = (qb0 < 512) ? ((512 - qb0) >> 6) : 0;

    // staging map: key-row = tid>>2 (0..63), two 16B chunks per thread
    const int srow  = tid >> 2;
    const int scol0 = (tid & 3) * 16;

    // ---- Q B-frags: two 16-query groups per wave ----
    const int qwmin = qb0 + wid * 32;
    const int qwmax = qwmin + 31;
    int qa[2];
    bfrag bq0[2], bq1[2];
#pragma unroll
    for (int qg = 0; qg < 2; qg++) {
        qa[qg] = qwmin + qg * 16 + n16;
        bq0[qg] = *(const bfrag*)(&QK[(bS + qa[qg]) * LQK + hoff + quad * 8]);
        bq1[qg] = *(const bfrag*)(&QK[(bS + qa[qg]) * LQK + hoff + 32 + quad * 8]);
    }

    f32x4 ao[2][4];                     // O^T per group: d = j*16+quad*4+r
#pragma unroll
    for (int qg = 0; qg < 2; qg++)
#pragma unroll
        for (int j = 0; j < 4; j++) ao[qg][j] = (f32x4){0.f, 0.f, 0.f, 0.f};
    float m[2] = {-1e30f, -1e30f}, l[2] = {0.f, 0.f};

    // prefetch K for first iteration
    uint4 kp0, kp1;
    {
        const bf16_t* src = &QK[(bS + wstart + it0 * 64 + srow) * LQK + 1024 + hoff + scol0];
        kp0 = *(const uint4*)(src);
        kp1 = *(const uint4*)(src + 8);
    }

    for (int it = it0; it < 10; ++it) {
        const int k0 = wstart + it * 64;
        const int pb = it & 1;
        *(uint4*)(&Ks[pb][srow * 72 + scol0])     = kp0;
        *(uint4*)(&Ks[pb][srow * 72 + scol0 + 8]) = kp1;
        __syncthreads();
        if (it < 9) {
            const bf16_t* src = &QK[(bS + wstart + (it + 1) * 64 + srow) * LQK + 1024 + hoff + scol0];
            kp0 = *(const uint4*)(src);
            kp1 = *(const uint4*)(src + 8);
        }

        // wave-uniform skip: none of this wave's 32 queries attend these keys
        if (k0 > qwmax || k0 + 63 < qwmin - 511) continue;

        // ---- S^T = K Q^T : K frags shared across both query groups ----
        f32x4 a[2][4];
#pragma unroll
        for (int nt = 0; nt < 4; nt++) {
            bfrag ak0 = *(const bfrag*)(&Ks[pb][(nt * 16 + n16) * 72 + quad * 8]);
            bfrag ak1 = *(const bfrag*)(&Ks[pb][(nt * 16 + n16) * 72 + 32 + quad * 8]);
#pragma unroll
            for (int qg = 0; qg < 2; qg++) {
                f32x4 s4 = (f32x4){0.f, 0.f, 0.f, 0.f};
                s4 = __builtin_amdgcn_mfma_f32_16x16x32_bf16(ak0, bq0[qg], s4, 0, 0, 0);
                s4 = __builtin_amdgcn_mfma_f32_16x16x32_bf16(ak1, bq1[qg], s4, 0, 0, 0);
                a[qg][nt] = s4;
            }
        }

#pragma unroll
        for (int qg = 0; qg < 2; qg++) {
            // per-group mask (scores already carry the 1/8 scale)
            const int gmin = qwmin + qg * 16, gmax = gmin + 15;
            const bool msk = !((k0 >= gmax - 511) & (k0 + 63 <= gmin));
            if (msk) {
#pragma unroll
                for (int nt = 0; nt < 4; nt++)
#pragma unroll
                    for (int r = 0; r < 4; r++) {
                        int ka = k0 + nt * 16 + quad * 4 + r;   // S^T row = key
                        bool valid = (ka >= qa[qg] - 511) & (ka <= qa[qg]);
                        if (!valid) a[qg][nt][r] = -1e30f;
                    }
            }

            // online softmax: per-lane scalar state
            float cm = -1e30f;
#pragma unroll
            for (int nt = 0; nt < 4; nt++)
#pragma unroll
                for (int r = 0; r < 4; r++) cm = fmaxf(cm, a[qg][nt][r]);
            cm = fmaxf(cm, __shfl_xor(cm, 16, 64));
            cm = fmaxf(cm, __shfl_xor(cm, 32, 64));
            float mn    = fmaxf(m[qg], cm);
            float alpha = __expf(m[qg] - mn);
            m[qg] = mn;
#pragma unroll
            for (int j = 0; j < 4; j++)
#pragma unroll
                for (int r = 0; r < 4; r++) ao[qg][j][r] *= alpha;

            // p = exp(s-m) (underflows to 0 for masked); packed b64 into Pw
            float lacc = 0.f;
#pragma unroll
            for (int nt = 0; nt < 4; nt++) {
                bf16x4 pk;
#pragma unroll
                for (int r = 0; r < 4; r++) {
                    float p = __expf(a[qg][nt][r] - m[qg]);
                    lacc += p;
                    pk[r] = (__bf16)p;
                }
                *(bf16x4*)&Pw[wid][(qg * 16 + n16) * PSTR + nt * 16 + quad * 4] = pk;
            }
            l[qg] = l[qg] * alpha + lacc;
        }

        // ---- O^T += V^T P^T : V frags shared across both query groups ----
#pragma unroll
        for (int ks = 0; ks < 2; ks++) {
            bfrag bp[2];
#pragma unroll
            for (int qg = 0; qg < 2; qg++)
                bp[qg] = *(const bfrag*)(&Pw[wid][(qg * 16 + n16) * PSTR + ks * 32 + quad * 8]);
#pragma unroll
            for (int j = 0; j < 4; j++) {
                bfrag av = *(const bfrag*)(&Vb[(size_t)(j * 16 + n16) * SEQ
                                               + k0 + ks * 32 + quad * 8]);
#pragma unroll
                for (int qg = 0; qg < 2; qg++)
                    ao[qg][j] = __builtin_amdgcn_mfma_f32_16x16x32_bf16(av, bp[qg], ao[qg][j], 0, 0, 0);
            }
        }
    }

    // ---- epilogue: reduce l across quads, store O rows (packed b64) ----
#pragma unroll
    for (int qg = 0; qg < 2; qg++) {
        float lv = l[qg];
        lv += __shfl_xor(lv, 16, 64);
        lv += __shfl_xor(lv, 32, 64);
        const float inv = 1.0f / lv;
#pragma unroll
        for (int j = 0; j < 4; j++) {
            bf16x4 pk;
#pragma unroll
            for (int r = 0; r < 4; r++) pk[r] = (__bf16)(ao[qg][j][r] * inv);
            *(bf16x4*)&AO[(bS + qa[qg]) * NDIM + hoff + j * 16 + quad * 4] = pk;
        }
    }
}

// ---------------------------------------------------------------------------
extern "C" void kernel_launch(void* const* d_in, const int* in_sizes, int n_in,
                              void* d_out, int out_size, void* d_ws, size_t ws_size,
                              hipStream_t stream)
{
    const float* x  = (const float*)d_in[0];
    const float* Wq = (const float*)d_in[1];
    const float* bq = (const float*)d_in[2];
    const float* Wk = (const float*)d_in[3];
    const float* bk = (const float*)d_in[4];
    const float* Wv = (const float*)d_in[5];
    const float* bv = (const float*)d_in[6];
    const float* Wo = (const float*)d_in[7];
    const float* bo = (const float*)d_in[8];
    float* out = (float*)d_out;

    // ws: QKb [8192][2048] bf16 (32 MiB) | AbX [8192][1024] bf16 (16 MiB)
    //     Wc [Wq|Wk|Wv|Wo] bf16 (8 MiB)
    const size_t QK_E = (size_t)MROWS * LQK;
    const size_t X_E  = (size_t)MROWS * NDIM;
    if (ws_size < (QK_E + X_E + 4u * 1048576u) * sizeof(bf16_t)) return;

    bf16_t* QKb = (bf16_t*)d_ws;
    bf16_t* AbX = QKb + QK_E;
    bf16_t* Wc  = AbX + X_E;
    bf16_t* Wob = Wc + 3u * 1048576u;
    bf16_t* Vtg = (bf16_t*)d_out;   // scratch inside out buf; dead before O-proj

    dim3 blk(256);

    cast_x<<<dim3(4096), blk, 0, stream>>>(x, AbX);
    cast_w<<<dim3(2048), blk, 0, stream>>>(Wq, Wk, Wv, Wo, Wc);

    // fused QKV projection: Q,K -> QKb (stride 2048); V -> Vtg transposed
    gemm_bt<bf16_t><<<dim3(3072 / 128, MROWS / 128), blk, 0, stream>>>(
        AbX, NDIM, Wc, bq, bk, bv, 0.125f, QKb, LQK, NDIM, Vtg);

    attn_win<<<dim3(1024), dim3(256), 0, stream>>>(QKb, Vtg, AbX);

    // output projection: [8192,1024] x [1024,1024]^T -> fp32 out
    gemm_bt<float><<<dim3(NDIM / 128, MROWS / 128), blk, 0, stream>>>(
        AbX, NDIM, Wob, bo, bo, bo, 1.0f, out, NDIM, NDIM, nullptr);
}